// Round 3
// baseline (2783.820 us; speedup 1.0000x reference)
//
#include <hip/hip_runtime.h>
#include <hip/hip_bf16.h>
#include <cmath>

typedef __hip_bfloat16 bf16;

#define Cc    180
#define Hh    112
#define Wwid  112
#define Ltok  12544
#define Bsz   2
#define TOK   25088
#define WSz   7
#define NHd   6
#define DHd   30
#define NWIN  256
#define P49   49

// Dual-dtype input access: flag==1 -> float32 inputs, flag==0 -> bf16.
__device__ __forceinline__ float LD(const void* p, size_t i, int f) {
    if (f) return ((const float*)p)[i];
    return (float)((const bf16*)p)[i];
}
__device__ __forceinline__ void ST(void* p, size_t i, int f, float v) {
    if (f) ((float*)p)[i] = v;
    else   ((bf16*)p)[i] = (bf16)v;
}

__device__ __forceinline__ float wred(float v) {
    v += __shfl_xor(v, 1);
    v += __shfl_xor(v, 2);
    v += __shfl_xor(v, 4);
    v += __shfl_xor(v, 8);
    v += __shfl_xor(v, 16);
    v += __shfl_xor(v, 32);
    return v;
}

// ---- dtype detect: bf16 N(0,1) data never has exponent >= 0xC8; f32 data
// read as u16 halves certainly does (mantissa halves ~ uniform bits). -------
__global__ void k_detect(const unsigned short* __restrict__ xb, int* __restrict__ flag) {
    __shared__ int s;
    if (threadIdx.x == 0) s = 0;
    __syncthreads();
    int bad = 0;
    for (int i = threadIdx.x; i < 2048; i += 256) {
        int e = (xb[i] >> 7) & 0xFF;
        if (e >= 0xC8) bad = 1;
    }
    if (bad) atomicOr(&s, 1);
    __syncthreads();
    if (threadIdx.x == 0) flag[0] = s;
}

// ---- patch norm: x(B,C,H,W) -> T(B,L,C) f32 --------------------------------
__global__ __launch_bounds__(256) void k_patchnorm(const void* __restrict__ x,
                                                   const void* __restrict__ g,
                                                   const void* __restrict__ b,
                                                   float* __restrict__ T,
                                                   const int* __restrict__ dflag) {
    int f = *dflag;
    int tokid = blockIdx.x * 4 + (threadIdx.x >> 6);
    int lane  = threadIdx.x & 63;
    int bb = tokid / Ltok, ll = tokid % Ltok;
    size_t base = (size_t)bb * Cc * Ltok + ll;
    float v0 = LD(x, base + (size_t)lane * Ltok, f);
    float v1 = LD(x, base + (size_t)(lane + 64) * Ltok, f);
    float v2 = (lane < 52) ? LD(x, base + (size_t)(lane + 128) * Ltok, f) : 0.f;
    float s  = wred(v0 + v1 + v2);
    float sq = wred(v0 * v0 + v1 * v1 + v2 * v2);
    float mean = s * (1.f / 180.f);
    float var  = sq * (1.f / 180.f) - mean * mean;
    float rstd = rsqrtf(var + 1e-5f);
    float* tp = T + (size_t)tokid * Cc;
    tp[lane]      = (v0 - mean) * rstd * LD(g, lane, f)      + LD(b, lane, f);
    tp[lane + 64] = (v1 - mean) * rstd * LD(g, lane + 64, f) + LD(b, lane + 64, f);
    if (lane < 52)
        tp[lane + 128] = (v2 - mean) * rstd * LD(g, lane + 128, f) + LD(b, lane + 128, f);
}

// ---- LN (+ optional shifted-window gather), bf16 out. goff = element offset
// of this block's gamma/beta inside the stacked (NB,C) arrays. --------------
__global__ __launch_bounds__(256) void k_ln(const float* __restrict__ T,
                                            const void* __restrict__ g,
                                            const void* __restrict__ b,
                                            bf16* __restrict__ D,
                                            int windowed, int shift, int goff,
                                            const int* __restrict__ dflag) {
    int f = *dflag;
    int r    = blockIdx.x * 4 + (threadIdx.x >> 6);
    int lane = threadIdx.x & 63;
    int src;
    if (windowed) {
        int bb  = r / (NWIN * P49);
        int rem = r % (NWIN * P49);
        int wi = rem / P49, p = rem % P49;
        int wy = wi >> 4, wx = wi & 15;
        int py = p / 7, px = p % 7;
        int gh = (wy * 7 + py + shift) % Hh;
        int gw = (wx * 7 + px + shift) % Wwid;
        src = bb * Ltok + gh * Wwid + gw;
    } else {
        src = r;
    }
    const float* tp = T + (size_t)src * Cc;
    float v0 = tp[lane];
    float v1 = tp[lane + 64];
    float v2 = (lane < 52) ? tp[lane + 128] : 0.f;
    float s  = wred(v0 + v1 + v2);
    float sq = wred(v0 * v0 + v1 * v1 + v2 * v2);
    float mean = s * (1.f / 180.f);
    float var  = sq * (1.f / 180.f) - mean * mean;
    float rstd = rsqrtf(var + 1e-5f);
    bf16* dp = D + (size_t)r * Cc;
    dp[lane]      = (bf16)((v0 - mean) * rstd * LD(g, goff + lane, f)      + LD(b, goff + lane, f));
    dp[lane + 64] = (bf16)((v1 - mean) * rstd * LD(g, goff + lane + 64, f) + LD(b, goff + lane + 64, f));
    if (lane < 52)
        dp[lane + 128] = (bf16)((v2 - mean) * rstd * LD(g, goff + lane + 128, f) + LD(b, goff + lane + 128, f));
}

// ---- final LN -> out(B,C,H,W), out dtype per flag --------------------------
__global__ __launch_bounds__(256) void k_final(const float* __restrict__ T,
                                               const void* __restrict__ g,
                                               const void* __restrict__ b,
                                               void* __restrict__ out,
                                               const int* __restrict__ dflag) {
    int f = *dflag;
    int tokid = blockIdx.x * 4 + (threadIdx.x >> 6);
    int lane  = threadIdx.x & 63;
    int bb = tokid / Ltok, ll = tokid % Ltok;
    const float* tp = T + (size_t)tokid * Cc;
    float v0 = tp[lane];
    float v1 = tp[lane + 64];
    float v2 = (lane < 52) ? tp[lane + 128] : 0.f;
    float s  = wred(v0 + v1 + v2);
    float sq = wred(v0 * v0 + v1 * v1 + v2 * v2);
    float mean = s * (1.f / 180.f);
    float var  = sq * (1.f / 180.f) - mean * mean;
    float rstd = rsqrtf(var + 1e-5f);
    size_t base = (size_t)bb * Cc * Ltok + ll;
    ST(out, base + (size_t)lane * Ltok,        f, (v0 - mean) * rstd * LD(g, lane, f)      + LD(b, lane, f));
    ST(out, base + (size_t)(lane + 64) * Ltok, f, (v1 - mean) * rstd * LD(g, lane + 64, f) + LD(b, lane + 64, f));
    if (lane < 52)
        ST(out, base + (size_t)(lane + 128) * Ltok, f,
           (v2 - mean) * rstd * LD(g, lane + 128, f) + LD(b, lane + 128, f));
}

// ---- tiled GEMM: Out = A(bf16 MxK, chunk-local) @ W(KxN) + bias ------------
// woff/boff = element offsets of this block's W/bias slices.
// EPI: 0 store bf16, 1 gelu+store bf16, 2 T[rowoff+row]+=, 3 shifted scatter.
template <int EPI>
__global__ __launch_bounds__(256) void k_gemm(const bf16* __restrict__ A,
                                              const void* __restrict__ Wt,
                                              const void* __restrict__ bias,
                                              bf16* __restrict__ OutB,
                                              float* __restrict__ OutF,
                                              int M, int N, int K, int shift, int rowoff,
                                              size_t woff, size_t boff,
                                              const int* __restrict__ dflag) {
    int f = *dflag;
    __shared__ float As[16][64];
    __shared__ float Bs[16][65];
    int tid = threadIdx.x;
    int m0 = blockIdx.y * 64, n0 = blockIdx.x * 64;
    int ty = tid >> 4, tx = tid & 15;
    float acc[4][4] = {};

    for (int k0 = 0; k0 < K; k0 += 16) {
        {
            int kk = tid & 15, row = tid >> 4;
#pragma unroll
            for (int rr = 0; rr < 4; ++rr) {
                int rrow = row + rr * 16;
                float v = 0.f;
                if (k0 + kk < K) v = (float)A[(size_t)(m0 + rrow) * K + k0 + kk];
                As[kk][rrow] = v;
            }
        }
        {
            int col = tid & 63, kb = tid >> 6;
#pragma unroll
            for (int rr = 0; rr < 4; ++rr) {
                int kk = kb + rr * 4;
                float v = 0.f;
                if (k0 + kk < K && n0 + col < N)
                    v = LD(Wt, woff + (size_t)(k0 + kk) * N + n0 + col, f);
                Bs[kk][col] = v;
            }
        }
        __syncthreads();
#pragma unroll
        for (int kk = 0; kk < 16; ++kk) {
            float a[4], bb[4];
#pragma unroll
            for (int m = 0; m < 4; ++m) a[m] = As[kk][ty * 4 + m];
#pragma unroll
            for (int n = 0; n < 4; ++n) bb[n] = Bs[kk][tx * 4 + n];
#pragma unroll
            for (int m = 0; m < 4; ++m)
#pragma unroll
                for (int n = 0; n < 4; ++n) acc[m][n] += a[m] * bb[n];
        }
        __syncthreads();
    }

#pragma unroll
    for (int m = 0; m < 4; ++m) {
        int row  = m0 + ty * 4 + m;
        int grow = rowoff + row;
        int tgt_tok = grow;
        if (EPI == 3) {
            int bb  = grow / (NWIN * P49);
            int rem = grow % (NWIN * P49);
            int wi = rem / P49, p = rem % P49;
            int wy = wi >> 4, wx = wi & 15;
            int py = p / 7, px = p % 7;
            int gh = (wy * 7 + py + shift) % Hh;
            int gw = (wx * 7 + px + shift) % Wwid;
            tgt_tok = bb * Ltok + gh * Wwid + gw;
        }
#pragma unroll
        for (int n = 0; n < 4; ++n) {
            int col = n0 + tx * 4 + n;
            if (col < N) {
                float val = acc[m][n] + LD(bias, boff + col, f);
                if (EPI == 0) {
                    OutB[(size_t)row * N + col] = (bf16)val;
                } else if (EPI == 1) {
                    val = 0.5f * val * (1.f + erff(val * 0.70710678118654752f));
                    OutB[(size_t)row * N + col] = (bf16)val;
                } else if (EPI == 2) {
                    OutF[(size_t)grow * Cc + col] += val;
                } else {
                    OutF[(size_t)tgt_tok * Cc + col] += val;
                }
            }
        }
    }
}

// ---- windowed attention: one block per (window, head) ----------------------
__device__ __forceinline__ int regionOf(int g, int shift) {
    return (g < Hh - WSz) ? 0 : ((g < Hh - shift) ? 1 : 2);
}

__global__ __launch_bounds__(128) void k_attn(const bf16* __restrict__ QKV,
                                              bf16* __restrict__ Ow,
                                              const void* __restrict__ rpb,
                                              int shift, int w0, size_t rpboff,
                                              const int* __restrict__ dflag) {
    int f = *dflag;
    __shared__ float q[P49][DHd];
    __shared__ float k[P49][DHd];
    __shared__ float v[P49][DHd];
    __shared__ float S[P49][P49];
    int lw = blockIdx.x / NHd;
    int hd = blockIdx.x % NHd;
    int bw = w0 + lw;
    int r0l = lw * P49;
    int r0g = bw * P49;
    int tid = threadIdx.x;
    const float scale = 0.18257418583505536f;

    for (int idx = tid; idx < P49 * DHd; idx += 128) {
        int p = idx / DHd, d = idx % DHd;
        const bf16* base = QKV + (size_t)(r0l + p) * 540 + hd * DHd + d;
        q[p][d] = (float)base[0] * scale;
        k[p][d] = (float)base[180];
        v[p][d] = (float)base[360];
    }
    __syncthreads();

    int wi = bw & (NWIN - 1);
    int wy = wi >> 4, wx = wi & 15;
    for (int idx = tid; idx < P49 * P49; idx += 128) {
        int i = idx / P49, j = idx % P49;
        float dot = 0.f;
#pragma unroll
        for (int d = 0; d < DHd; ++d) dot += q[i][d] * k[j][d];
        int ih = i / 7, iw = i % 7, jh = j / 7, jw = j % 7;
        int rel = (ih - jh + 6) * 13 + (iw - jw + 6);
        dot += LD(rpb, rpboff + (size_t)rel * NHd + hd, f);
        if (shift) {
            int li = regionOf(wy * 7 + ih, shift) * 3 + regionOf(wx * 7 + iw, shift);
            int lj = regionOf(wy * 7 + jh, shift) * 3 + regionOf(wx * 7 + jw, shift);
            if (li != lj) dot -= 100.f;
        }
        S[i][j] = dot;
    }
    __syncthreads();

    if (tid < P49) {
        float m = -1e30f;
        for (int j = 0; j < P49; ++j) m = fmaxf(m, S[tid][j]);
        float s = 0.f;
        for (int j = 0; j < P49; ++j) {
            float e = __expf(S[tid][j] - m);
            S[tid][j] = e;
            s += e;
        }
        float inv = 1.f / s;
        for (int j = 0; j < P49; ++j) S[tid][j] *= inv;
    }
    __syncthreads();

    for (int idx = tid; idx < P49 * DHd; idx += 128) {
        int p = idx / DHd, d = idx % DHd;
        float o = 0.f;
#pragma unroll
        for (int j = 0; j < P49; ++j) o += S[p][j] * v[j][d];
        Ow[(size_t)(r0g + p) * Cc + hd * DHd + d] = (bf16)o;
    }
}

// ---------------------------------------------------------------------------
extern "C" void kernel_launch(void* const* d_in, const int* in_sizes, int n_in,
                              void* d_out, int out_size, void* d_ws, size_t ws_size,
                              hipStream_t stream) {
    const void* x      = d_in[0];
    const void* pe_g   = d_in[1];
    const void* pe_b   = d_in[2];
    const void* ln1_g  = d_in[3];
    const void* ln1_b  = d_in[4];
    const void* qkv_w  = d_in[5];
    const void* qkv_b  = d_in[6];
    const void* proj_w = d_in[7];
    const void* proj_b = d_in[8];
    const void* ln2_g  = d_in[9];
    const void* ln2_b  = d_in[10];
    const void* fc1_w  = d_in[11];
    const void* fc1_b  = d_in[12];
    const void* fc2_w  = d_in[13];
    const void* fc2_b  = d_in[14];
    const void* rpb    = d_in[15];
    const void* fn_g   = d_in[16];
    const void* fn_b   = d_in[17];

    // ws layout: [flag 256B][T f32 18.1MB][Abuf bf16 9.0MB][Bbuf bf16 chunked]
    int*   dflag = (int*)d_ws;
    float* T     = (float*)((char*)d_ws + 256);
    bf16*  Abuf  = (bf16*)(T + (size_t)TOK * Cc);
    bf16*  Bbuf  = Abuf + (size_t)TOK * Cc;
    size_t fixed = 256 + (size_t)TOK * Cc * 4 + (size_t)TOK * Cc * 2;

    int c = 1;   // chunks; CM stays a multiple of 64 and CW integral for c<=8
    while (c < 8 && fixed + (size_t)(TOK / c) * 720 * 2 > ws_size) c <<= 1;
    int CM = TOK / c;
    int CW = (Bsz * NWIN) / c;

    dim3 b256(256);
    k_detect<<<1, b256, 0, stream>>>((const unsigned short*)x, dflag);
    k_patchnorm<<<TOK / 4, b256, 0, stream>>>(x, pe_g, pe_b, T, dflag);

    const int shifts[4] = {0, 3, 0, 3};
    for (int i = 0; i < 4; ++i) {
        int sh = shifts[i];
        k_ln<<<TOK / 4, b256, 0, stream>>>(T, ln1_g, ln1_b, Abuf, 1, sh, i * Cc, dflag);
        for (int j = 0; j < c; ++j) {
            int R0 = j * CM;
            dim3 g1((540 + 63) / 64, CM / 64);
            k_gemm<0><<<g1, b256, 0, stream>>>(Abuf + (size_t)R0 * Cc, qkv_w, qkv_b,
                                               Bbuf, nullptr, CM, 540, Cc, 0, 0,
                                               (size_t)i * Cc * 540, (size_t)i * 540, dflag);
            k_attn<<<CW * NHd, 128, 0, stream>>>(Bbuf, Abuf, rpb, sh, j * CW,
                                                 (size_t)i * 169 * NHd, dflag);
            dim3 g2((Cc + 63) / 64, CM / 64);
            k_gemm<3><<<g2, b256, 0, stream>>>(Abuf + (size_t)R0 * Cc, proj_w, proj_b,
                                               nullptr, T, CM, Cc, Cc, sh, R0,
                                               (size_t)i * Cc * Cc, (size_t)i * Cc, dflag);
        }
        k_ln<<<TOK / 4, b256, 0, stream>>>(T, ln2_g, ln2_b, Abuf, 0, 0, i * Cc, dflag);
        for (int j = 0; j < c; ++j) {
            int R0 = j * CM;
            dim3 g3((720 + 63) / 64, CM / 64);
            k_gemm<1><<<g3, b256, 0, stream>>>(Abuf + (size_t)R0 * Cc, fc1_w, fc1_b,
                                               Bbuf, nullptr, CM, 720, Cc, 0, 0,
                                               (size_t)i * Cc * 720, (size_t)i * 720, dflag);
            dim3 g4((Cc + 63) / 64, CM / 64);
            k_gemm<2><<<g4, b256, 0, stream>>>(Bbuf, fc2_w, fc2_b,
                                               nullptr, T, CM, Cc, 720, 0, R0,
                                               (size_t)i * 720 * Cc, (size_t)i * Cc, dflag);
        }
    }

    k_final<<<TOK / 4, b256, 0, stream>>>(T, fn_g, fn_b, d_out, dflag);
}

// Round 4
// 1096.512 us; speedup vs baseline: 2.5388x; 2.5388x over previous
//
#include <hip/hip_runtime.h>
#include <hip/hip_bf16.h>
#include <cmath>

typedef __hip_bfloat16 bf16;
typedef short short8 __attribute__((ext_vector_type(8)));   // 8 bf16 (4 VGPRs)
typedef float f32x4  __attribute__((ext_vector_type(4)));   // MFMA acc

#define Cc    180
#define KP1   192      // 180 padded to mult of 32
#define KP2   736      // 720 padded to mult of 32
#define Hh    112
#define Wwid  112
#define Ltok  12544
#define Bsz   2
#define TOK   25088
#define WSz   7
#define NHd   6
#define DHd   30
#define NWIN  256
#define P49   49

// Dual-dtype input access: flag==1 -> float32 inputs, flag==0 -> bf16.
__device__ __forceinline__ float LD(const void* p, size_t i, int f) {
    if (f) return ((const float*)p)[i];
    return (float)((const bf16*)p)[i];
}
__device__ __forceinline__ void ST(void* p, size_t i, int f, float v) {
    if (f) ((float*)p)[i] = v;
    else   ((bf16*)p)[i] = (bf16)v;
}

__device__ __forceinline__ float wred(float v) {
    v += __shfl_xor(v, 1);
    v += __shfl_xor(v, 2);
    v += __shfl_xor(v, 4);
    v += __shfl_xor(v, 8);
    v += __shfl_xor(v, 16);
    v += __shfl_xor(v, 32);
    return v;
}

// ---- dtype detect (bf16 N(0,1) never has exponent >= 0xC8) -----------------
__global__ void k_detect(const unsigned short* __restrict__ xb, int* __restrict__ flag) {
    __shared__ int s;
    if (threadIdx.x == 0) s = 0;
    __syncthreads();
    int bad = 0;
    for (int i = threadIdx.x; i < 2048; i += 256) {
        int e = (xb[i] >> 7) & 0xFF;
        if (e >= 0xC8) bad = 1;
    }
    if (bad) atomicOr(&s, 1);
    __syncthreads();
    if (threadIdx.x == 0) flag[0] = s;
}

// ---- weight transpose+pad: dst(Npad x Kp) <- src(K x N), zeros outside -----
__global__ __launch_bounds__(256) void k_tr(const void* __restrict__ src, size_t woff,
                                            bf16* __restrict__ dst,
                                            int K, int N, int Kp, int Npad,
                                            const int* __restrict__ dflag) {
    int f = *dflag;
    int idx = blockIdx.x * 256 + threadIdx.x;
    if (idx >= Npad * Kp) return;
    int n = idx / Kp, k = idx % Kp;
    float v = (n < N && k < K) ? LD(src, woff + (size_t)k * N + n, f) : 0.f;
    dst[idx] = (bf16)v;
}

// ---- patch norm: x(B,C,H,W) -> T(B,L,C) f32 --------------------------------
__global__ __launch_bounds__(256) void k_patchnorm(const void* __restrict__ x,
                                                   const void* __restrict__ g,
                                                   const void* __restrict__ b,
                                                   float* __restrict__ T,
                                                   const int* __restrict__ dflag) {
    int f = *dflag;
    int tokid = blockIdx.x * 4 + (threadIdx.x >> 6);
    int lane  = threadIdx.x & 63;
    int bb = tokid / Ltok, ll = tokid % Ltok;
    size_t base = (size_t)bb * Cc * Ltok + ll;
    float v0 = LD(x, base + (size_t)lane * Ltok, f);
    float v1 = LD(x, base + (size_t)(lane + 64) * Ltok, f);
    float v2 = (lane < 52) ? LD(x, base + (size_t)(lane + 128) * Ltok, f) : 0.f;
    float s  = wred(v0 + v1 + v2);
    float sq = wred(v0 * v0 + v1 * v1 + v2 * v2);
    float mean = s * (1.f / 180.f);
    float var  = sq * (1.f / 180.f) - mean * mean;
    float rstd = rsqrtf(var + 1e-5f);
    float* tp = T + (size_t)tokid * Cc;
    tp[lane]      = (v0 - mean) * rstd * LD(g, lane, f)      + LD(b, lane, f);
    tp[lane + 64] = (v1 - mean) * rstd * LD(g, lane + 64, f) + LD(b, lane + 64, f);
    if (lane < 52)
        tp[lane + 128] = (v2 - mean) * rstd * LD(g, lane + 128, f) + LD(b, lane + 128, f);
}

// ---- LN (+ optional shifted-window gather) -> bf16 rows at stride KP1 ------
// Pad cols [180,192) written as zeros (lanes 52..63 of group 3).
__global__ __launch_bounds__(256) void k_ln(const float* __restrict__ T,
                                            const void* __restrict__ g,
                                            const void* __restrict__ b,
                                            bf16* __restrict__ D,
                                            int windowed, int shift, int goff,
                                            const int* __restrict__ dflag) {
    int f = *dflag;
    int r    = blockIdx.x * 4 + (threadIdx.x >> 6);
    int lane = threadIdx.x & 63;
    int src;
    if (windowed) {
        int bb  = r / (NWIN * P49);
        int rem = r % (NWIN * P49);
        int wi = rem / P49, p = rem % P49;
        int wy = wi >> 4, wx = wi & 15;
        int py = p / 7, px = p % 7;
        int gh = (wy * 7 + py + shift) % Hh;
        int gw = (wx * 7 + px + shift) % Wwid;
        src = bb * Ltok + gh * Wwid + gw;
    } else {
        src = r;
    }
    const float* tp = T + (size_t)src * Cc;
    float v0 = tp[lane];
    float v1 = tp[lane + 64];
    float v2 = (lane < 52) ? tp[lane + 128] : 0.f;
    float s  = wred(v0 + v1 + v2);
    float sq = wred(v0 * v0 + v1 * v1 + v2 * v2);
    float mean = s * (1.f / 180.f);
    float var  = sq * (1.f / 180.f) - mean * mean;
    float rstd = rsqrtf(var + 1e-5f);
    bf16* dp = D + (size_t)r * KP1;
    dp[lane]      = (bf16)((v0 - mean) * rstd * LD(g, goff + lane, f)      + LD(b, goff + lane, f));
    dp[lane + 64] = (bf16)((v1 - mean) * rstd * LD(g, goff + lane + 64, f) + LD(b, goff + lane + 64, f));
    if (lane < 52)
        dp[lane + 128] = (bf16)((v2 - mean) * rstd * LD(g, goff + lane + 128, f) + LD(b, goff + lane + 128, f));
    else
        dp[lane + 128] = (bf16)0.f;   // zero pad cols 180..191
}

// ---- final LN -> out(B,C,H,W), out dtype per flag --------------------------
__global__ __launch_bounds__(256) void k_final(const float* __restrict__ T,
                                               const void* __restrict__ g,
                                               const void* __restrict__ b,
                                               void* __restrict__ out,
                                               const int* __restrict__ dflag) {
    int f = *dflag;
    int tokid = blockIdx.x * 4 + (threadIdx.x >> 6);
    int lane  = threadIdx.x & 63;
    int bb = tokid / Ltok, ll = tokid % Ltok;
    const float* tp = T + (size_t)tokid * Cc;
    float v0 = tp[lane];
    float v1 = tp[lane + 64];
    float v2 = (lane < 52) ? tp[lane + 128] : 0.f;
    float s  = wred(v0 + v1 + v2);
    float sq = wred(v0 * v0 + v1 * v1 + v2 * v2);
    float mean = s * (1.f / 180.f);
    float var  = sq * (1.f / 180.f) - mean * mean;
    float rstd = rsqrtf(var + 1e-5f);
    size_t base = (size_t)bb * Cc * Ltok + ll;
    ST(out, base + (size_t)lane * Ltok,        f, (v0 - mean) * rstd * LD(g, lane, f)      + LD(b, lane, f));
    ST(out, base + (size_t)(lane + 64) * Ltok, f, (v1 - mean) * rstd * LD(g, lane + 64, f) + LD(b, lane + 64, f));
    if (lane < 52)
        ST(out, base + (size_t)(lane + 128) * Ltok, f,
           (v2 - mean) * rstd * LD(g, lane + 128, f) + LD(b, lane + 128, f));
}

// ---- MFMA GEMM: Out(M x N) = A(M x Kp, bf16) @ Wt^T + bias -----------------
// Wt is pre-transposed (Npad x Kp) with zero padding. Block tile 128x64,
// 4 waves in 2x2, each wave 64x32 via 4x2 MFMA 16x16x32 tiles. Fragment-major
// LDS: [tile][lane][8] so all LDS traffic is contiguous b128.
// EPI: 0 store bf16 (qkv), 1 gelu+store bf16 (fc1), 2 T+= (fc2),
//      3 T+= shifted-window scatter (proj).
template <int EPI>
__global__ __launch_bounds__(256) void k_mgemm(const bf16* __restrict__ A,
                                               const bf16* __restrict__ Wt,
                                               const void* __restrict__ bias,
                                               size_t boff, int Nbias,
                                               bf16* __restrict__ OutB, int ldOut, int Nstore,
                                               float* __restrict__ OutF,
                                               int Kp, int shift, int rowoff,
                                               const int* __restrict__ dflag) {
    __shared__ __align__(16) short Als[8 * 64 * 8];   // 8 KB
    __shared__ __align__(16) short Bls[4 * 64 * 8];   // 4 KB
    int tid  = threadIdx.x;
    int lane = tid & 63;
    int w    = tid >> 6;
    int wr   = w >> 1, wc = w & 1;
    int m0 = blockIdx.y * 128;
    int n0 = blockIdx.x * 64;
    int m_lo = lane & 15, q = lane >> 4;

    f32x4 acc[4][2] = {};

    for (int k0 = 0; k0 < Kp; k0 += 32) {
        // stage A chunk (128 x 32) as fragments: 512 runs of 16B
#pragma unroll
        for (int s = 0; s < 2; ++s) {
            int ri = tid + s * 256;
            int mt = ri >> 6, ln = ri & 63;
            const bf16* src = A + (size_t)(m0 + mt * 16 + (ln & 15)) * Kp + k0 + (ln >> 4) * 8;
            *(ulonglong2*)(&Als[ri * 8]) = *(const ulonglong2*)src;
        }
        {   // stage B chunk (64 x 32): 256 runs of 16B
            int ri = tid;
            int nt = ri >> 6, ln = ri & 63;
            const bf16* src = Wt + (size_t)(n0 + nt * 16 + (ln & 15)) * Kp + k0 + (ln >> 4) * 8;
            *(ulonglong2*)(&Bls[ri * 8]) = *(const ulonglong2*)src;
        }
        __syncthreads();
        short8 b0 = *(const short8*)&Bls[((wc * 2 + 0) * 64 + lane) * 8];
        short8 b1 = *(const short8*)&Bls[((wc * 2 + 1) * 64 + lane) * 8];
#pragma unroll
        for (int mt = 0; mt < 4; ++mt) {
            short8 a = *(const short8*)&Als[((wr * 4 + mt) * 64 + lane) * 8];
            acc[mt][0] = __builtin_amdgcn_mfma_f32_16x16x32_bf16(a, b0, acc[mt][0], 0, 0, 0);
            acc[mt][1] = __builtin_amdgcn_mfma_f32_16x16x32_bf16(a, b1, acc[mt][1], 0, 0, 0);
        }
        __syncthreads();
    }

    int f = *dflag;
#pragma unroll
    for (int mt = 0; mt < 4; ++mt) {
#pragma unroll
        for (int nt = 0; nt < 2; ++nt) {
#pragma unroll
            for (int r = 0; r < 4; ++r) {
                int row = m0 + (wr * 4 + mt) * 16 + q * 4 + r;   // C/D: row=(lane>>4)*4+reg
                int col = n0 + (wc * 2 + nt) * 16 + m_lo;        //      col=lane&15
                float val = acc[mt][nt][r];
                if (EPI == 0) {
                    if (col < Nstore)
                        OutB[(size_t)row * ldOut + col] = (bf16)(val + LD(bias, boff + col, f));
                } else if (EPI == 1) {
                    float bv = (col < Nbias) ? LD(bias, boff + col, f) : 0.f;
                    val += bv;
                    val = 0.5f * val * (1.f + erff(val * 0.70710678118654752f));
                    if (col < Nstore) OutB[(size_t)row * ldOut + col] = (bf16)val;
                } else if (EPI == 2) {
                    if (col < Nstore)
                        OutF[(size_t)(rowoff + row) * Cc + col] += val + LD(bias, boff + col, f);
                } else {  // EPI == 3: shifted-window scatter into residual T
                    if (col < Nstore) {
                        int grow = rowoff + row;
                        int bb  = grow / (NWIN * P49);
                        int rem = grow % (NWIN * P49);
                        int wi = rem / P49, p = rem % P49;
                        int wy = wi >> 4, wx = wi & 15;
                        int py = p / 7, px = p % 7;
                        int gh = (wy * 7 + py + shift) % Hh;
                        int gw = (wx * 7 + px + shift) % Wwid;
                        int tgt = bb * Ltok + gh * Wwid + gw;
                        OutF[(size_t)tgt * Cc + col] += val + LD(bias, boff + col, f);
                    }
                }
            }
        }
    }
}

// ---- windowed attention: one block per (window, head) ----------------------
__device__ __forceinline__ int regionOf(int g, int shift) {
    return (g < Hh - WSz) ? 0 : ((g < Hh - shift) ? 1 : 2);
}

__global__ __launch_bounds__(128) void k_attn(const bf16* __restrict__ QKV,
                                              bf16* __restrict__ Ow,
                                              const void* __restrict__ rpb,
                                              int shift, int w0, size_t rpboff,
                                              const int* __restrict__ dflag) {
    int f = *dflag;
    __shared__ float q[P49][DHd];
    __shared__ float k[P49][DHd];
    __shared__ float v[P49][DHd];
    __shared__ float S[P49][P49];
    int lw = blockIdx.x / NHd;
    int hd = blockIdx.x % NHd;
    int bw = w0 + lw;
    int r0l = lw * P49;
    int r0g = bw * P49;
    int tid = threadIdx.x;
    const float scale = 0.18257418583505536f;

    for (int idx = tid; idx < P49 * DHd; idx += 128) {
        int p = idx / DHd, d = idx % DHd;
        const bf16* base = QKV + (size_t)(r0l + p) * 540 + hd * DHd + d;
        q[p][d] = (float)base[0] * scale;
        k[p][d] = (float)base[180];
        v[p][d] = (float)base[360];
    }
    __syncthreads();

    int wi = bw & (NWIN - 1);
    int wy = wi >> 4, wx = wi & 15;
    for (int idx = tid; idx < P49 * P49; idx += 128) {
        int i = idx / P49, j = idx % P49;
        float dot = 0.f;
#pragma unroll
        for (int d = 0; d < DHd; ++d) dot += q[i][d] * k[j][d];
        int ih = i / 7, iw = i % 7, jh = j / 7, jw = j % 7;
        int rel = (ih - jh + 6) * 13 + (iw - jw + 6);
        dot += LD(rpb, rpboff + (size_t)rel * NHd + hd, f);
        if (shift) {
            int li = regionOf(wy * 7 + ih, shift) * 3 + regionOf(wx * 7 + iw, shift);
            int lj = regionOf(wy * 7 + jh, shift) * 3 + regionOf(wx * 7 + jw, shift);
            if (li != lj) dot -= 100.f;
        }
        S[i][j] = dot;
    }
    __syncthreads();

    if (tid < P49) {
        float m = -1e30f;
        for (int j = 0; j < P49; ++j) m = fmaxf(m, S[tid][j]);
        float s = 0.f;
        for (int j = 0; j < P49; ++j) {
            float e = __expf(S[tid][j] - m);
            S[tid][j] = e;
            s += e;
        }
        float inv = 1.f / s;
        for (int j = 0; j < P49; ++j) S[tid][j] *= inv;
    }
    __syncthreads();

    for (int idx = tid; idx < P49 * DHd; idx += 128) {
        int p = idx / DHd, d = idx % DHd;
        float o = 0.f;
#pragma unroll
        for (int j = 0; j < P49; ++j) o += S[p][j] * v[j][d];
        Ow[(size_t)(r0g + p) * KP1 + hd * DHd + d] = (bf16)o;
    }
    // zero pad cols [180,192) of this window's rows (hd==0 blocks only)
    if (hd == 0) {
        for (int idx = tid; idx < P49 * 12; idx += 128) {
            int p = idx / 12, cp = 180 + idx % 12;
            Ow[(size_t)(r0g + p) * KP1 + cp] = (bf16)0.f;
        }
    }
}

// ---------------------------------------------------------------------------
extern "C" void kernel_launch(void* const* d_in, const int* in_sizes, int n_in,
                              void* d_out, int out_size, void* d_ws, size_t ws_size,
                              hipStream_t stream) {
    const void* x      = d_in[0];
    const void* pe_g   = d_in[1];
    const void* pe_b   = d_in[2];
    const void* ln1_g  = d_in[3];
    const void* ln1_b  = d_in[4];
    const void* qkv_w  = d_in[5];
    const void* qkv_b  = d_in[6];
    const void* proj_w = d_in[7];
    const void* proj_b = d_in[8];
    const void* ln2_g  = d_in[9];
    const void* ln2_b  = d_in[10];
    const void* fc1_w  = d_in[11];
    const void* fc1_b  = d_in[12];
    const void* fc2_w  = d_in[13];
    const void* fc2_b  = d_in[14];
    const void* rpb    = d_in[15];
    const void* fn_g   = d_in[16];
    const void* fn_b   = d_in[17];

    // ws: [flag 256B][T f32][Abuf bf16 TOKxKP1][Wt 4 blocks][Bbuf bf16 chunked]
    const size_t wtQ = (size_t)576 * KP1, wtP = (size_t)192 * KP1;
    const size_t wtF1 = (size_t)768 * KP1, wtF2 = (size_t)192 * KP2;
    const size_t wtPerBlk = wtQ + wtP + wtF1 + wtF2;

    int*   dflag = (int*)d_ws;
    float* T     = (float*)((char*)d_ws + 256);
    bf16*  Abuf  = (bf16*)(T + (size_t)TOK * Cc);
    bf16*  Wts   = Abuf + (size_t)TOK * KP1;
    bf16*  Bbuf  = Wts + 4 * wtPerBlk;
    size_t fixed = (size_t)((char*)Bbuf - (char*)d_ws);

    int c = 1;   // chunk count; CM multiple of 128 required -> c in {1,2,4}
    while (c < 4 && fixed + (size_t)(TOK / c) * KP2 * 2 > ws_size) c <<= 1;
    int CM = TOK / c;
    int CW = (Bsz * NWIN) / c;

    dim3 b256(256);
    k_detect<<<1, b256, 0, stream>>>((const unsigned short*)x, dflag);

    // pre-transpose + pad all weights
    for (int i = 0; i < 4; ++i) {
        bf16* wq  = Wts + i * wtPerBlk;
        bf16* wp  = wq + wtQ;
        bf16* wf1 = wp + wtP;
        bf16* wf2 = wf1 + wtF1;
        k_tr<<<(int)((wtQ  + 255) / 256), b256, 0, stream>>>(qkv_w,  (size_t)i * Cc * 540, wq,  180, 540, KP1, 576, dflag);
        k_tr<<<(int)((wtP  + 255) / 256), b256, 0, stream>>>(proj_w, (size_t)i * Cc * Cc,  wp,  180, 180, KP1, 192, dflag);
        k_tr<<<(int)((wtF1 + 255) / 256), b256, 0, stream>>>(fc1_w,  (size_t)i * Cc * 720, wf1, 180, 720, KP1, 768, dflag);
        k_tr<<<(int)((wtF2 + 255) / 256), b256, 0, stream>>>(fc2_w,  (size_t)i * 720 * Cc, wf2, 720, 180, KP2, 192, dflag);
    }

    k_patchnorm<<<TOK / 4, b256, 0, stream>>>(x, pe_g, pe_b, T, dflag);

    const int shifts[4] = {0, 3, 0, 3};
    for (int i = 0; i < 4; ++i) {
        int sh = shifts[i];
        bf16* wq  = Wts + i * wtPerBlk;
        bf16* wp  = wq + wtQ;
        bf16* wf1 = wp + wtP;
        bf16* wf2 = wf1 + wtF1;

        k_ln<<<TOK / 4, b256, 0, stream>>>(T, ln1_g, ln1_b, Abuf, 1, sh, i * Cc, dflag);
        for (int j = 0; j < c; ++j) {
            int R0 = j * CM;
            dim3 g1(576 / 64, CM / 128);
            k_mgemm<0><<<g1, b256, 0, stream>>>(Abuf + (size_t)R0 * KP1, wq, qkv_b,
                                                (size_t)i * 540, 540, Bbuf, 540, 540,
                                                nullptr, KP1, 0, 0, dflag);
            k_attn<<<CW * NHd, 128, 0, stream>>>(Bbuf, Abuf, rpb, sh, j * CW,
                                                 (size_t)i * 169 * NHd, dflag);
            dim3 g2(192 / 64, CM / 128);
            k_mgemm<3><<<g2, b256, 0, stream>>>(Abuf + (size_t)R0 * KP1, wp, proj_b,
                                                (size_t)i * Cc, Cc, nullptr, 0, Cc,
                                                T, KP1, sh, R0, dflag);
        }
        k_ln<<<TOK / 4, b256, 0, stream>>>(T, ln2_g, ln2_b, Abuf, 0, 0, i * Cc, dflag);
        for (int j = 0; j < c; ++j) {
            int R0 = j * CM;
            dim3 g3(768 / 64, CM / 128);
            k_mgemm<1><<<g3, b256, 0, stream>>>(Abuf + (size_t)R0 * KP1, wf1, fc1_b,
                                                (size_t)i * 720, 720, Bbuf, KP2, KP2,
                                                nullptr, KP1, 0, 0, dflag);
            dim3 g4(192 / 64, CM / 128);
            k_mgemm<2><<<g4, b256, 0, stream>>>(Bbuf, wf2, fc2_b,
                                                (size_t)i * Cc, Cc, nullptr, 0, Cc,
                                                T, KP2, 0, R0, dflag);
        }
    }

    k_final<<<TOK / 4, b256, 0, stream>>>(T, fn_g, fn_b, d_out, dflag);
}

// Round 5
// 950.353 us; speedup vs baseline: 2.9292x; 1.1538x over previous
//
#include <hip/hip_runtime.h>
#include <hip/hip_bf16.h>
#include <cmath>

typedef __hip_bfloat16 bf16;
typedef short short8 __attribute__((ext_vector_type(8)));   // 8 bf16 (4 VGPRs)
typedef float f32x4  __attribute__((ext_vector_type(4)));   // MFMA acc

#define Cc    180
#define KP1   192      // 180 padded to mult of 32
#define KP2   736      // 720 padded to mult of 32
#define Hh    112
#define Wwid  112
#define Ltok  12544
#define Bsz   2
#define TOK   25088
#define WSz   7
#define NHd   6
#define DHd   30
#define NWIN  256
#define P49   49

// Dual-dtype input access: flag==1 -> float32 inputs, flag==0 -> bf16.
__device__ __forceinline__ float LD(const void* p, size_t i, int f) {
    if (f) return ((const float*)p)[i];
    return (float)((const bf16*)p)[i];
}
__device__ __forceinline__ void ST(void* p, size_t i, int f, float v) {
    if (f) ((float*)p)[i] = v;
    else   ((bf16*)p)[i] = (bf16)v;
}

__device__ __forceinline__ float wred(float v) {
    v += __shfl_xor(v, 1);
    v += __shfl_xor(v, 2);
    v += __shfl_xor(v, 4);
    v += __shfl_xor(v, 8);
    v += __shfl_xor(v, 16);
    v += __shfl_xor(v, 32);
    return v;
}

// ---- dtype detect (bf16 N(0,1) never has exponent >= 0xC8) -----------------
__global__ void k_detect(const unsigned short* __restrict__ xb, int* __restrict__ flag) {
    __shared__ int s;
    if (threadIdx.x == 0) s = 0;
    __syncthreads();
    int bad = 0;
    for (int i = threadIdx.x; i < 2048; i += 256) {
        int e = (xb[i] >> 7) & 0xFF;
        if (e >= 0xC8) bad = 1;
    }
    if (bad) atomicOr(&s, 1);
    __syncthreads();
    if (threadIdx.x == 0) flag[0] = s;
}

// ---- weight transpose+pad: dst(Npad x Kp) <- src(K x N), zeros outside -----
__global__ __launch_bounds__(256) void k_tr(const void* __restrict__ src, size_t woff,
                                            bf16* __restrict__ dst,
                                            int K, int N, int Kp, int Npad,
                                            const int* __restrict__ dflag) {
    int f = *dflag;
    int idx = blockIdx.x * 256 + threadIdx.x;
    if (idx >= Npad * Kp) return;
    int n = idx / Kp, k = idx % Kp;
    float v = (n < N && k < K) ? LD(src, woff + (size_t)k * N + n, f) : 0.f;
    dst[idx] = (bf16)v;
}

// ---- qkv weight transpose with head-padded column remap --------------------
// dst(576 x KP1): col n' -> sec=n'/192, hd, d (d<30 real, else zero col)
__global__ __launch_bounds__(256) void k_trq(const void* __restrict__ src, size_t woff,
                                             bf16* __restrict__ dst,
                                             const int* __restrict__ dflag) {
    int f = *dflag;
    int idx = blockIdx.x * 256 + threadIdx.x;
    if (idx >= 576 * KP1) return;
    int n = idx / KP1, k = idx % KP1;
    int sec = n / 192, rm = n % 192, hd = rm >> 5, d = rm & 31;
    float v = (d < 30 && k < 180) ? LD(src, woff + (size_t)k * 540 + sec * 180 + hd * 30 + d, f) : 0.f;
    dst[idx] = (bf16)v;
}

// ---- rpb expand: BT[6][64][64] f32, -1e9 in pads ---------------------------
__global__ __launch_bounds__(256) void k_bias(const void* __restrict__ rpb, size_t off,
                                              float* __restrict__ BT,
                                              const int* __restrict__ dflag) {
    int f = *dflag;
    int idx = blockIdx.x * 256 + threadIdx.x;
    if (idx >= NHd * 4096) return;
    int hd = idx >> 12, rem = idx & 4095;
    int i = rem >> 6, j = rem & 63;
    float v;
    if (i < 49 && j < 49) {
        int rel = (i / 7 - j / 7 + 6) * 13 + (i % 7 - j % 7 + 6);
        v = LD(rpb, off + (size_t)rel * NHd + hd, f);
    } else {
        v = -1.0e9f;
    }
    BT[idx] = v;
}

// ---- patch norm: x(B,C,H,W) -> T(B,L,C) f32 --------------------------------
__global__ __launch_bounds__(256) void k_patchnorm(const void* __restrict__ x,
                                                   const void* __restrict__ g,
                                                   const void* __restrict__ b,
                                                   float* __restrict__ T,
                                                   const int* __restrict__ dflag) {
    int f = *dflag;
    int tokid = blockIdx.x * 4 + (threadIdx.x >> 6);
    int lane  = threadIdx.x & 63;
    int bb = tokid / Ltok, ll = tokid % Ltok;
    size_t base = (size_t)bb * Cc * Ltok + ll;
    float v0 = LD(x, base + (size_t)lane * Ltok, f);
    float v1 = LD(x, base + (size_t)(lane + 64) * Ltok, f);
    float v2 = (lane < 52) ? LD(x, base + (size_t)(lane + 128) * Ltok, f) : 0.f;
    float s  = wred(v0 + v1 + v2);
    float sq = wred(v0 * v0 + v1 * v1 + v2 * v2);
    float mean = s * (1.f / 180.f);
    float var  = sq * (1.f / 180.f) - mean * mean;
    float rstd = rsqrtf(var + 1e-5f);
    float* tp = T + (size_t)tokid * Cc;
    tp[lane]      = (v0 - mean) * rstd * LD(g, lane, f)      + LD(b, lane, f);
    tp[lane + 64] = (v1 - mean) * rstd * LD(g, lane + 64, f) + LD(b, lane + 64, f);
    if (lane < 52)
        tp[lane + 128] = (v2 - mean) * rstd * LD(g, lane + 128, f) + LD(b, lane + 128, f);
}

// ---- LN (+ optional shifted-window gather) -> bf16 rows at stride KP1 ------
__global__ __launch_bounds__(256) void k_ln(const float* __restrict__ T,
                                            const void* __restrict__ g,
                                            const void* __restrict__ b,
                                            bf16* __restrict__ D,
                                            int windowed, int shift, int goff,
                                            const int* __restrict__ dflag) {
    int f = *dflag;
    int r    = blockIdx.x * 4 + (threadIdx.x >> 6);
    int lane = threadIdx.x & 63;
    int src;
    if (windowed) {
        int bb  = r / (NWIN * P49);
        int rem = r % (NWIN * P49);
        int wi = rem / P49, p = rem % P49;
        int wy = wi >> 4, wx = wi & 15;
        int py = p / 7, px = p % 7;
        int gh = (wy * 7 + py + shift) % Hh;
        int gw = (wx * 7 + px + shift) % Wwid;
        src = bb * Ltok + gh * Wwid + gw;
    } else {
        src = r;
    }
    const float* tp = T + (size_t)src * Cc;
    float v0 = tp[lane];
    float v1 = tp[lane + 64];
    float v2 = (lane < 52) ? tp[lane + 128] : 0.f;
    float s  = wred(v0 + v1 + v2);
    float sq = wred(v0 * v0 + v1 * v1 + v2 * v2);
    float mean = s * (1.f / 180.f);
    float var  = sq * (1.f / 180.f) - mean * mean;
    float rstd = rsqrtf(var + 1e-5f);
    bf16* dp = D + (size_t)r * KP1;
    dp[lane]      = (bf16)((v0 - mean) * rstd * LD(g, goff + lane, f)      + LD(b, goff + lane, f));
    dp[lane + 64] = (bf16)((v1 - mean) * rstd * LD(g, goff + lane + 64, f) + LD(b, goff + lane + 64, f));
    if (lane < 52)
        dp[lane + 128] = (bf16)((v2 - mean) * rstd * LD(g, goff + lane + 128, f) + LD(b, goff + lane + 128, f));
    else
        dp[lane + 128] = (bf16)0.f;
}

// ---- final LN -> out(B,C,H,W), out dtype per flag --------------------------
__global__ __launch_bounds__(256) void k_final(const float* __restrict__ T,
                                               const void* __restrict__ g,
                                               const void* __restrict__ b,
                                               void* __restrict__ out,
                                               const int* __restrict__ dflag) {
    int f = *dflag;
    int tokid = blockIdx.x * 4 + (threadIdx.x >> 6);
    int lane  = threadIdx.x & 63;
    int bb = tokid / Ltok, ll = tokid % Ltok;
    const float* tp = T + (size_t)tokid * Cc;
    float v0 = tp[lane];
    float v1 = tp[lane + 64];
    float v2 = (lane < 52) ? tp[lane + 128] : 0.f;
    float s  = wred(v0 + v1 + v2);
    float sq = wred(v0 * v0 + v1 * v1 + v2 * v2);
    float mean = s * (1.f / 180.f);
    float var  = sq * (1.f / 180.f) - mean * mean;
    float rstd = rsqrtf(var + 1e-5f);
    size_t base = (size_t)bb * Cc * Ltok + ll;
    ST(out, base + (size_t)lane * Ltok,        f, (v0 - mean) * rstd * LD(g, lane, f)      + LD(b, lane, f));
    ST(out, base + (size_t)(lane + 64) * Ltok, f, (v1 - mean) * rstd * LD(g, lane + 64, f) + LD(b, lane + 64, f));
    if (lane < 52)
        ST(out, base + (size_t)(lane + 128) * Ltok, f,
           (v2 - mean) * rstd * LD(g, lane + 128, f) + LD(b, lane + 128, f));
}

// ---- MFMA GEMM: Out(M x N) = A(M x Kp, bf16) @ Wt^T + bias -----------------
// EPI: 1 gelu+store bf16 (fc1), 2 T+= (fc2), 3 T+= shifted scatter (proj),
//      4 qkv split store: Q/K head-padded into OutB (ld 384, Q scaled), V
//      transposed into Vt[w][hd][d][p].
template <int EPI>
__global__ __launch_bounds__(256) void k_mgemm(const bf16* __restrict__ A,
                                               const bf16* __restrict__ Wt,
                                               const void* __restrict__ bias,
                                               size_t boff, int Nbias,
                                               bf16* __restrict__ OutB, int ldOut, int Nstore,
                                               float* __restrict__ OutF,
                                               bf16* __restrict__ Vt,
                                               int Kp, int shift, int rowoff,
                                               const int* __restrict__ dflag) {
    __shared__ __align__(16) short Als[8 * 64 * 8];
    __shared__ __align__(16) short Bls[4 * 64 * 8];
    int tid  = threadIdx.x;
    int lane = tid & 63;
    int w    = tid >> 6;
    int wr   = w >> 1, wc = w & 1;
    int m0 = blockIdx.y * 128;
    int n0 = blockIdx.x * 64;
    int m_lo = lane & 15, q = lane >> 4;

    f32x4 acc[4][2] = {};

    for (int k0 = 0; k0 < Kp; k0 += 32) {
#pragma unroll
        for (int s = 0; s < 2; ++s) {
            int ri = tid + s * 256;
            int mt = ri >> 6, ln = ri & 63;
            const bf16* src = A + (size_t)(m0 + mt * 16 + (ln & 15)) * Kp + k0 + (ln >> 4) * 8;
            *(ulonglong2*)(&Als[ri * 8]) = *(const ulonglong2*)src;
        }
        {
            int ri = tid;
            int nt = ri >> 6, ln = ri & 63;
            const bf16* src = Wt + (size_t)(n0 + nt * 16 + (ln & 15)) * Kp + k0 + (ln >> 4) * 8;
            *(ulonglong2*)(&Bls[ri * 8]) = *(const ulonglong2*)src;
        }
        __syncthreads();
        short8 b0 = *(const short8*)&Bls[((wc * 2 + 0) * 64 + lane) * 8];
        short8 b1 = *(const short8*)&Bls[((wc * 2 + 1) * 64 + lane) * 8];
#pragma unroll
        for (int mt = 0; mt < 4; ++mt) {
            short8 a = *(const short8*)&Als[((wr * 4 + mt) * 64 + lane) * 8];
            acc[mt][0] = __builtin_amdgcn_mfma_f32_16x16x32_bf16(a, b0, acc[mt][0], 0, 0, 0);
            acc[mt][1] = __builtin_amdgcn_mfma_f32_16x16x32_bf16(a, b1, acc[mt][1], 0, 0, 0);
        }
        __syncthreads();
    }

    int f = *dflag;
#pragma unroll
    for (int mt = 0; mt < 4; ++mt) {
#pragma unroll
        for (int nt = 0; nt < 2; ++nt) {
#pragma unroll
            for (int r = 0; r < 4; ++r) {
                int row = m0 + (wr * 4 + mt) * 16 + q * 4 + r;
                int col = n0 + (wc * 2 + nt) * 16 + m_lo;
                float val = acc[mt][nt][r];
                if (EPI == 1) {
                    float bv = (col < Nbias) ? LD(bias, boff + col, f) : 0.f;
                    val += bv;
                    val = 0.5f * val * (1.f + erff(val * 0.70710678118654752f));
                    if (col < Nstore) OutB[(size_t)row * ldOut + col] = (bf16)val;
                } else if (EPI == 2) {
                    if (col < Nstore)
                        OutF[(size_t)(rowoff + row) * Cc + col] += val + LD(bias, boff + col, f);
                } else if (EPI == 3) {
                    if (col < Nstore) {
                        int grow = rowoff + row;
                        int bb  = grow / (NWIN * P49);
                        int rem = grow % (NWIN * P49);
                        int wi = rem / P49, p = rem % P49;
                        int wy = wi >> 4, wx = wi & 15;
                        int py = p / 7, px = p % 7;
                        int gh = (wy * 7 + py + shift) % Hh;
                        int gw = (wx * 7 + px + shift) % Wwid;
                        int tgt = bb * Ltok + gh * Wwid + gw;
                        OutF[(size_t)tgt * Cc + col] += val + LD(bias, boff + col, f);
                    }
                } else {  // EPI == 4: qkv
                    int sec = col / 192, rm = col % 192;
                    int hd = rm >> 5, d = rm & 31;
                    float bv = (d < 30) ? LD(bias, boff + sec * 180 + hd * 30 + d, f) : 0.f;
                    val += bv;
                    if (sec == 0) val *= 0.18257418583505536f;   // pre-scale Q
                    if (sec < 2) {
                        OutB[(size_t)row * 384 + sec * 192 + hd * 32 + d] = (bf16)val;
                    } else {
                        int wloc = row / 49, p = row % 49;
                        Vt[(((size_t)wloc * NHd + hd) * 32 + d) * 64 + p] = (bf16)val;
                    }
                }
            }
        }
    }
}

// ---- MFMA attention: one wave per (window, head) ---------------------------
__device__ __forceinline__ int regionOf(int g, int shift) {
    return (g < Hh - WSz) ? 0 : ((g < Hh - shift) ? 1 : 2);
}

__global__ __launch_bounds__(64) void k_mattn(const bf16* __restrict__ QK,
                                              const bf16* __restrict__ Vt,
                                              const float* __restrict__ BT,
                                              bf16* __restrict__ Ow,
                                              int shift, int w0) {
    __shared__ __align__(16) bf16 P[64 * 72];
    int lane = threadIdx.x;
    int lw = blockIdx.x / NHd, hd = blockIdx.x % NHd;
    int r0 = lw * P49;
    int q = lane >> 4, c = lane & 15;

    // Q/K fragments straight from global (head-padded layout, 16B per lane)
    const bf16* qb = QK + (size_t)(r0 + c) * 384 + hd * 32 + q * 8;
    short8 qf[4], kf[4];
#pragma unroll
    for (int t = 0; t < 4; ++t) {
        qf[t] = *(const short8*)(qb + (size_t)t * 16 * 384);
        kf[t] = *(const short8*)(qb + 192 + (size_t)t * 16 * 384);
    }
    f32x4 zero = {0.f, 0.f, 0.f, 0.f};
    f32x4 S[4][4];
#pragma unroll
    for (int mt = 0; mt < 4; ++mt)
#pragma unroll
        for (int nt = 0; nt < 4; ++nt)
            S[mt][nt] = __builtin_amdgcn_mfma_f32_16x16x32_bf16(qf[mt], kf[nt], zero, 0, 0, 0);

    // bias + shift-mask, row max
    const float* bt = BT + hd * 4096;
    int wi = (w0 + lw) & (NWIN - 1);
    int wy = wi >> 4, wx = wi & 15;
    int lj[4], li[4][4];
    if (shift) {
#pragma unroll
        for (int nt = 0; nt < 4; ++nt) {
            int j = nt * 16 + c;
            lj[nt] = (j < 49) ? regionOf(wy * 7 + j / 7, shift) * 3 + regionOf(wx * 7 + j % 7, shift) : -1;
        }
#pragma unroll
        for (int mt = 0; mt < 4; ++mt)
#pragma unroll
            for (int r = 0; r < 4; ++r) {
                int i = mt * 16 + q * 4 + r;
                li[mt][r] = (i < 49) ? regionOf(wy * 7 + i / 7, shift) * 3 + regionOf(wx * 7 + i % 7, shift) : -2;
            }
    }
    float rmax[4][4];
#pragma unroll
    for (int mt = 0; mt < 4; ++mt)
#pragma unroll
        for (int r = 0; r < 4; ++r) rmax[mt][r] = -3.0e38f;
#pragma unroll
    for (int mt = 0; mt < 4; ++mt)
#pragma unroll
        for (int nt = 0; nt < 4; ++nt)
#pragma unroll
            for (int r = 0; r < 4; ++r) {
                int i = mt * 16 + q * 4 + r, j = nt * 16 + c;
                float v = S[mt][nt][r] + bt[i * 64 + j];
                if (shift && li[mt][r] != lj[nt]) v -= 100.f;
                S[mt][nt][r] = v;
                rmax[mt][r] = fmaxf(rmax[mt][r], v);
            }
#pragma unroll
    for (int mt = 0; mt < 4; ++mt)
#pragma unroll
        for (int r = 0; r < 4; ++r) {
            float m = rmax[mt][r];
            m = fmaxf(m, __shfl_xor(m, 1));
            m = fmaxf(m, __shfl_xor(m, 2));
            m = fmaxf(m, __shfl_xor(m, 4));
            m = fmaxf(m, __shfl_xor(m, 8));
            rmax[mt][r] = m;
        }
    float rsum[4][4] = {};
#pragma unroll
    for (int mt = 0; mt < 4; ++mt)
#pragma unroll
        for (int nt = 0; nt < 4; ++nt)
#pragma unroll
            for (int r = 0; r < 4; ++r) {
                float e = __expf(S[mt][nt][r] - rmax[mt][r]);
                S[mt][nt][r] = e;
                rsum[mt][r] += e;
            }
#pragma unroll
    for (int mt = 0; mt < 4; ++mt)
#pragma unroll
        for (int r = 0; r < 4; ++r) {
            float s = rsum[mt][r];
            s += __shfl_xor(s, 1);
            s += __shfl_xor(s, 2);
            s += __shfl_xor(s, 4);
            s += __shfl_xor(s, 8);
            rsum[mt][r] = 1.f / s;
        }
    // P (bf16) -> LDS, 72-stride to break b128 bank aliasing
#pragma unroll
    for (int mt = 0; mt < 4; ++mt)
#pragma unroll
        for (int nt = 0; nt < 4; ++nt)
#pragma unroll
            for (int r = 0; r < 4; ++r)
                P[(mt * 16 + q * 4 + r) * 72 + nt * 16 + c] = (bf16)(S[mt][nt][r] * rsum[mt][r]);
    __syncthreads();

    // PV: A = P (LDS b128), B = Vt rows (global 16B)
    f32x4 O[4][2] = {};
    const bf16* vb = Vt + (((size_t)lw * NHd + hd) * 32 + c) * 64 + q * 8;
#pragma unroll
    for (int ks = 0; ks < 2; ++ks) {
        short8 vf0 = *(const short8*)(vb + ks * 32);
        short8 vf1 = *(const short8*)(vb + 16 * 64 + ks * 32);
#pragma unroll
        for (int mt = 0; mt < 4; ++mt) {
            short8 pf = *(const short8*)&P[(mt * 16 + c) * 72 + ks * 32 + q * 8];
            O[mt][0] = __builtin_amdgcn_mfma_f32_16x16x32_bf16(pf, vf0, O[mt][0], 0, 0, 0);
            O[mt][1] = __builtin_amdgcn_mfma_f32_16x16x32_bf16(pf, vf1, O[mt][1], 0, 0, 0);
        }
    }
    // store O -> Ow (window-slot rows, head cols), global row base
    int r0g = (w0 + lw) * P49;
#pragma unroll
    for (int mt = 0; mt < 4; ++mt)
#pragma unroll
        for (int nt = 0; nt < 2; ++nt)
#pragma unroll
            for (int r = 0; r < 4; ++r) {
                int i = mt * 16 + q * 4 + r, d = nt * 16 + c;
                if (i < 49 && d < 30)
                    Ow[(size_t)(r0g + i) * KP1 + hd * 30 + d] = (bf16)O[mt][nt][r];
            }
    if (hd == 0) {
        for (int idx = lane; idx < P49 * 12; idx += 64) {
            int p = idx / 12, cp = 180 + idx % 12;
            Ow[(size_t)(r0g + p) * KP1 + cp] = (bf16)0.f;
        }
    }
}

// ---------------------------------------------------------------------------
extern "C" void kernel_launch(void* const* d_in, const int* in_sizes, int n_in,
                              void* d_out, int out_size, void* d_ws, size_t ws_size,
                              hipStream_t stream) {
    const void* x      = d_in[0];
    const void* pe_g   = d_in[1];
    const void* pe_b   = d_in[2];
    const void* ln1_g  = d_in[3];
    const void* ln1_b  = d_in[4];
    const void* qkv_w  = d_in[5];
    const void* qkv_b  = d_in[6];
    const void* proj_w = d_in[7];
    const void* proj_b = d_in[8];
    const void* ln2_g  = d_in[9];
    const void* ln2_b  = d_in[10];
    const void* fc1_w  = d_in[11];
    const void* fc1_b  = d_in[12];
    const void* fc2_w  = d_in[13];
    const void* fc2_b  = d_in[14];
    const void* rpb    = d_in[15];
    const void* fn_g   = d_in[16];
    const void* fn_b   = d_in[17];

    const size_t wtQ = (size_t)576 * KP1, wtP = (size_t)192 * KP1;
    const size_t wtF1 = (size_t)768 * KP1, wtF2 = (size_t)192 * KP2;
    const size_t wtPerBlk = wtQ + wtP + wtF1 + wtF2;

    // ws: [flag 256B][T f32][Abuf][Wts][BT f32][Vt (chunk)][Bbuf (chunk)]
    int*   dflag = (int*)d_ws;
    float* T     = (float*)((char*)d_ws + 256);
    bf16*  Abuf  = (bf16*)(T + (size_t)TOK * Cc);
    bf16*  Wts   = Abuf + (size_t)TOK * KP1;
    float* BT    = (float*)(Wts + 4 * wtPerBlk);
    bf16*  Vt    = (bf16*)(BT + NHd * 4096);
    size_t fixed = (size_t)((char*)Vt - (char*)d_ws);

    int c = 1;   // chunks; CM must stay a multiple of 128 -> c in {1,2,4}
    while (c < 4 && fixed + ((size_t)(Bsz * NWIN / c) * NHd * 32 * 64
                             + (size_t)(TOK / c) * KP2) * 2 > ws_size) c <<= 1;
    int CM = TOK / c;
    int CW = (Bsz * NWIN) / c;
    bf16* Bbuf = Vt + (size_t)CW * NHd * 32 * 64;   // QK (ld 384) / fc1 out (ld 736)

    dim3 b256(256);
    k_detect<<<1, b256, 0, stream>>>((const unsigned short*)x, dflag);

    for (int i = 0; i < 4; ++i) {
        bf16* wq  = Wts + i * wtPerBlk;
        bf16* wp  = wq + wtQ;
        bf16* wf1 = wp + wtP;
        bf16* wf2 = wf1 + wtF1;
        k_trq<<<(int)((wtQ + 255) / 256), b256, 0, stream>>>(qkv_w, (size_t)i * Cc * 540, wq, dflag);
        k_tr<<<(int)((wtP  + 255) / 256), b256, 0, stream>>>(proj_w, (size_t)i * Cc * Cc,  wp,  180, 180, KP1, 192, dflag);
        k_tr<<<(int)((wtF1 + 255) / 256), b256, 0, stream>>>(fc1_w,  (size_t)i * Cc * 720, wf1, 180, 720, KP1, 768, dflag);
        k_tr<<<(int)((wtF2 + 255) / 256), b256, 0, stream>>>(fc2_w,  (size_t)i * 720 * Cc, wf2, 720, 180, KP2, 192, dflag);
    }

    k_patchnorm<<<TOK / 4, b256, 0, stream>>>(x, pe_g, pe_b, T, dflag);

    const int shifts[4] = {0, 3, 0, 3};
    for (int i = 0; i < 4; ++i) {
        int sh = shifts[i];
        bf16* wq  = Wts + i * wtPerBlk;
        bf16* wp  = wq + wtQ;
        bf16* wf1 = wp + wtP;
        bf16* wf2 = wf1 + wtF1;

        k_bias<<<(NHd * 4096 + 255) / 256, b256, 0, stream>>>(rpb, (size_t)i * 169 * NHd, BT, dflag);
        k_ln<<<TOK / 4, b256, 0, stream>>>(T, ln1_g, ln1_b, Abuf, 1, sh, i * Cc, dflag);
        for (int j = 0; j < c; ++j) {
            int R0 = j * CM;
            dim3 g1(576 / 64, CM / 128);
            k_mgemm<4><<<g1, b256, 0, stream>>>(Abuf + (size_t)R0 * KP1, wq, qkv_b,
                                                (size_t)i * 540, 540, Bbuf, 384, 576,
                                                nullptr, Vt, KP1, 0, 0, dflag);
            k_mattn<<<CW * NHd, 64, 0, stream>>>(Bbuf, Vt, BT, Abuf, sh, j * CW);
            dim3 g2(192 / 64, CM / 128);
            k_mgemm<3><<<g2, b256, 0, stream>>>(Abuf + (size_t)R0 * KP1, wp, proj_b,
                                                (size_t)i * Cc, Cc, nullptr, 0, Cc,
                                                T, nullptr, KP1, sh, R0, dflag);
        }
        k_ln<<<TOK / 4, b256, 0, stream>>>(T, ln2_g, ln2_b, Abuf, 0, 0, i * Cc, dflag);
        for (int j = 0; j < c; ++j) {
            int R0 = j * CM;
            dim3 g3(768 / 64, CM / 128);
            k_mgemm<1><<<g3, b256, 0, stream>>>(Abuf + (size_t)R0 * KP1, wf1, fc1_b,
                                                (size_t)i * 720, 720, Bbuf, KP2, KP2,
                                                nullptr, nullptr, KP1, 0, 0, dflag);
            dim3 g4(192 / 64, CM / 128);
            k_mgemm<2><<<g4, b256, 0, stream>>>(Bbuf, wf2, fc2_b,
                                                (size_t)i * Cc, Cc, nullptr, 0, Cc,
                                                T, nullptr, KP2, 0, R0, dflag);
        }
    }

    k_final<<<TOK / 4, b256, 0, stream>>>(T, fn_g, fn_b, d_out, dflag);
}